// Round 5
// baseline (571.023 us; speedup 1.0000x reference)
//
#include <hip/hip_runtime.h>

// Problem constants
#define D 512
#define H 20
#define V 32000
#define T 1024
#define NT2 500    // 2 * (V/128) lse partials per row
#define NPART 16   // scan y partials per column j

typedef unsigned int uint;
typedef __attribute__((ext_vector_type(8))) short short8;
typedef __attribute__((ext_vector_type(4))) float floatx4;

#define CC 2.8853900817779268f      // 2*log2(e)
#define M2C -5.7707801635558537f    // -2*CC

__device__ __forceinline__ unsigned short f2bf(float f) {
    unsigned u = __builtin_bit_cast(unsigned, f);
    u += 0x7fffu + ((u >> 16) & 1u);   // round-to-nearest-even
    return (unsigned short)(u >> 16);
}

// VALU-pipe cross-lane ops via DPP (no LDS pipe!)
template <int CTRL>
__device__ __forceinline__ float dpp_add(float v) {
    int x = __builtin_amdgcn_update_dpp(0, __builtin_bit_cast(int, v), CTRL, 0xf, 0xf, true);
    return v + __builtin_bit_cast(float, x);
}
template <int CTRL>
__device__ __forceinline__ float dpp_max(float v) {
    int x = __builtin_amdgcn_update_dpp(0, __builtin_bit_cast(int, v), CTRL, 0xf, 0xf, true);
    return fmaxf(v, __builtin_bit_cast(float, x));
}
// reduce 16 contiguous lanes -> all 16 hold the result
__device__ __forceinline__ float reduce16(float v) {
    v = dpp_add<0xB1>(v);    // quad_perm xor 1
    v = dpp_add<0x4E>(v);    // quad_perm xor 2
    v = dpp_add<0x141>(v);   // row_half_mirror
    v = dpp_add<0x140>(v);   // row_mirror
    return v;
}
__device__ __forceinline__ float reduce16max(float v) {
    v = dpp_max<0xB1>(v);
    v = dpp_max<0x4E>(v);
    v = dpp_max<0x141>(v);
    v = dpp_max<0x140>(v);
    return v;
}

// ---------------------------------------------------------------- K1: gather
__global__ __launch_bounds__(256) void gather_kernel(const int* __restrict__ tokens,
                                                     const float* __restrict__ embed,
                                                     float* __restrict__ xs,
                                                     float* __restrict__ loss_acc) {
    int idx = blockIdx.x * 256 + threadIdx.x;     // float4 units, T*D/4 = 131072
    if (idx == 0) *loss_acc = 0.f;                // zero the loss accumulator
    int row = idx >> 7;                            // D/4 = 128 float4 per row
    int c   = idx & 127;
    float4 v = ((const float4*)(embed + (long)tokens[row] * D))[c];
    ((float4*)xs)[idx] = v;
}

// ------------------------- K2: z0 = (eta*CC) * xs@wa ; z1 = xs@wb  (fp32)
__global__ __launch_bounds__(256) void zgemm_kernel(const float* __restrict__ xs,
                                                    const float* __restrict__ wa,
                                                    const float* __restrict__ wb,
                                                    const float* __restrict__ eta_p,
                                                    float* __restrict__ z0,
                                                    float* __restrict__ z1) {
    __shared__ float Xs[16 * 36];   // [k][m], 32 m, padded
    __shared__ float Ws[16 * 68];   // [k][n], 64 n, padded
    const int tid = threadIdx.x;
    const int n0 = blockIdx.x * 64, m0 = blockIdx.y * 32;
    const float* Wm = blockIdx.z ? wb : wa;
    float* Z = blockIdx.z ? z1 : z0;
    const float sc = blockIdx.z ? 1.0f : (*eta_p) * CC;
    const int tx = tid & 15, ty = tid >> 4;
    const int xr = tid >> 3, xk = (tid & 7) * 2;
    const int wr = tid >> 4, wc = (tid & 15) * 4;
    float acc[2][4] = {};
    for (int k0 = 0; k0 < D; k0 += 16) {
        float2 xv = *(const float2*)(xs + (m0 + xr) * D + k0 + xk);
        float4 wv = *(const float4*)(Wm + (k0 + wr) * D + n0 + wc);
        Xs[(xk + 0) * 36 + xr] = xv.x;
        Xs[(xk + 1) * 36 + xr] = xv.y;
        *(float4*)(Ws + wr * 68 + wc) = wv;
        __syncthreads();
#pragma unroll
        for (int k = 0; k < 16; k++) {
            float a0 = Xs[k * 36 + 2 * ty];
            float a1 = Xs[k * 36 + 2 * ty + 1];
            float4 b = *(const float4*)(Ws + k * 68 + tx * 4);
            float bv[4] = {b.x, b.y, b.z, b.w};
#pragma unroll
            for (int c = 0; c < 4; c++) {
                acc[0][c] = __builtin_fmaf(a0, bv[c], acc[0][c]);
                acc[1][c] = __builtin_fmaf(a1, bv[c], acc[1][c]);
            }
        }
        __syncthreads();
    }
    float4 v0 = {sc * acc[0][0], sc * acc[0][1], sc * acc[0][2], sc * acc[0][3]};
    float4 v1 = {sc * acc[1][0], sc * acc[1][1], sc * acc[1][2], sc * acc[1][3]};
    *(float4*)(Z + (m0 + 2 * ty + 0) * D + n0 + tx * 4) = v0;
    *(float4*)(Z + (m0 + 2 * ty + 1) * D + n0 + tx * 4) = v1;
}

// ------------------------------------------------------------------ K3: scan
// 2048 single-wave blocks: block = (column j, row-quarter q). Lane owns two
// ADJACENT rows fw[q*128+2*lane][j], fw[+1][j] (float2 loads). z0 carries
// eta*CC; state pre-scaled by CC. A/B register double-buffer, no pinning.
// Reduction: reduce16 ONLY (pure VALU DPP). Lanes 0/16/32/48 hold 32-row
// partials for 8 consecutive t's -> stored as TWO float4s to the TRANSPOSED
// partial tensor ypart[plane][j][t] (contiguous in t, L2 merges to full
// lines; fixes r4's 284 MB scatter-write amplification).
#define LOADC(B, tbase)                                                       \
    {                                                                         \
        _Pragma("unroll")                                                     \
        for (int c = 0; c < 8; c++) {                                         \
            const int tr = ((tbase) + c) * D;                                 \
            za##B[c] = *(const float2*)(z0 + tr + i0);                        \
            xa##B[c] = *(const float2*)(xs + tr + i0);                        \
            ez##B[c] = z1[tr + j];                                            \
        }                                                                     \
    }

#define COMPUTE(B, tbase)                                                     \
    {                                                                         \
        float p[8];                                                           \
        _Pragma("unroll")                                                     \
        for (int c = 0; c < 8; c++) {                                         \
            float e = ez##B[c];                                               \
            float a0 = __builtin_amdgcn_exp2f(__builtin_fmaf(e, za##B[c].x, g0)); \
            float a1 = __builtin_amdgcn_exp2f(__builtin_fmaf(e, za##B[c].y, g1)); \
            float r0 = __builtin_amdgcn_rcpf(a0 + 1.0f);                      \
            float r1 = __builtin_amdgcn_rcpf(a1 + 1.0f);                      \
            g0 = __builtin_fmaf(M2C, r0, CC);                                 \
            g1 = __builtin_fmaf(M2C, r1, CC);                                 \
            p[c] = __builtin_fmaf(xa##B[c].y, g1, xa##B[c].x * g0);           \
        }                                                                     \
        _Pragma("unroll")                                                     \
        for (int c = 0; c < 8; c++) p[c] = reduce16(p[c]);                    \
        if ((lane & 15) == 0) {                                               \
            float4 s0 = {p[0], p[1], p[2], p[3]};                             \
            float4 s1 = {p[4], p[5], p[6], p[7]};                             \
            *(float4*)(yp + (tbase)) = s0;                                    \
            *(float4*)(yp + (tbase) + 4) = s1;                                \
        }                                                                     \
    }

__global__ __launch_bounds__(64) void scan_kernel(const float* __restrict__ z0,
                                                  const float* __restrict__ z1,
                                                  const float* __restrict__ xs,
                                                  const float* __restrict__ fw_init,
                                                  float* __restrict__ ypart) {
    const int lane = threadIdx.x;          // 64
    const int bid = blockIdx.x;            // 2048
    const int j = bid & 511;
    const int q = bid >> 9;                // row quarter 0..3
    const int i0 = q * 128 + 2 * lane;     // two adjacent rows per lane
    float g0 = CC * fw_init[(long)i0 * D + j];
    float g1 = CC * fw_init[(long)(i0 + 1) * D + j];
    // transposed partial plane: ypart[(plane*512 + j)*T + t], plane = q*4+(lane>>4)
    float* yp = ypart + ((long)(q * 4 + (lane >> 4)) * 512 + j) * T;

    float2 zaA[8], xaA[8], zaB[8], xaB[8];
    float  ezA[8], ezB[8];

    LOADC(A, 0);
    for (int t0 = 0; t0 < T; t0 += 16) {
        LOADC(B, t0 + 8);
        COMPUTE(A, t0);
        if (t0 + 16 < T) { LOADC(A, t0 + 16); }
        COMPUTE(B, t0 + 8);
    }
}

// ---------------- K4: fused MLP: y = sum(16 partials)/CC; h = selu(y@Aw+Ab);
//                   mixed = bf16(0.5*(h@Bw+Bb) + 0.5*xs). One block per token.
// Reads the TRANSPOSED ypart [plane][d][t] (gather, stride T across lanes).
// Block->t remap keeps 128 consecutive t's on one XCD so the 16-t line reuse
// hits that XCD's L2.
__global__ __launch_bounds__(256) void mlp_fused_kernel(const float* __restrict__ ypart,
                                                        const float* __restrict__ xs,
                                                        const float* __restrict__ Aw,
                                                        const float* __restrict__ Ab,
                                                        const float* __restrict__ Bw,
                                                        const float* __restrict__ Bb,
                                                        unsigned short* __restrict__ mixed) {
    const int bid = blockIdx.x, tid = threadIdx.x;
    const int t = ((bid & 7) << 7) | (bid >> 3);   // bijective on [0,1024)
    __shared__ float y_lds[D];
    __shared__ float h_lds[H];
    const float INVC = 0.34657359027997264f;   // 1/CC = ln2/2
    // phase 1: gather-sum the 16 scan partials, un-scale
#pragma unroll
    for (int s = 0; s < 2; s++) {
        int d = s * 256 + tid;
        float v = 0.f;
#pragma unroll
        for (int p = 0; p < NPART; p++)
            v += ypart[((long)p * 512 + d) * T + t];
        y_lds[d] = v * INVC;
    }
    __syncthreads();
    // phase 2: h[20] — wave w computes jj = w*5..w*5+4 via full-wave dots
    const int w = tid >> 6, lane = tid & 63;
    float yv[8];
#pragma unroll
    for (int k = 0; k < 8; k++) yv[k] = y_lds[k * 64 + lane];
#pragma unroll
    for (int u = 0; u < 5; u++) {
        const int jj = w * 5 + u;
        float a = 0.f;
#pragma unroll
        for (int k = 0; k < 8; k++)
            a = __builtin_fmaf(yv[k], Aw[(k * 64 + lane) * H + jj], a);
        a = reduce16(a);
        a += __shfl_xor(a, 16, 64);
        a += __shfl_xor(a, 32, 64);
        if (lane == 0) {
            a += Ab[jj];
            const float sc = 1.0507009873554805f, al = 1.6732632423543772f;
            h_lds[jj] = a > 0.f ? sc * a : sc * al * (__expf(a) - 1.f);
        }
    }
    __syncthreads();
    // phase 3: mixed
#pragma unroll
    for (int s = 0; s < 2; s++) {
        int d = s * 256 + tid;
        float o = Bb[d];
#pragma unroll
        for (int jj = 0; jj < H; jj++) o = __builtin_fmaf(h_lds[jj], Bw[jj * D + d], o);
        int gi = t * D + d;
        mixed[gi] = f2bf(0.5f * o + 0.5f * xs[gi]);
    }
}

// --------------------------------- K5a: head_w [K][N] f32 -> wt [N][K] bf16
__global__ __launch_bounds__(256) void convert_wt_kernel(const float* __restrict__ head_w,
                                                         unsigned short* __restrict__ wt) {
    __shared__ float tile[64 * 68];
    const int n0 = blockIdx.x * 64, k0 = blockIdx.y * 64;
    const int tid = threadIdx.x;
#pragma unroll
    for (int s = 0; s < 4; s++) {
        int idx4 = s * 256 + tid;            // 1024 float4 slots
        int r = idx4 >> 4, c4 = idx4 & 15;
        float4 v = *(const float4*)(head_w + (long)(k0 + r) * V + n0 + c4 * 4);
        *(float4*)(tile + r * 68 + c4 * 4) = v;
    }
    __syncthreads();
    const int rr = tid >> 2;                 // n within tile
    const int cq = tid & 3;                  // k quarter (16 k's)
    uint u[8];
#pragma unroll
    for (int p = 0; p < 8; p++) {
        float a = tile[(cq * 16 + p * 2 + 0) * 68 + rr];
        float b = tile[(cq * 16 + p * 2 + 1) * 68 + rr];
        u[p] = (uint)f2bf(a) | ((uint)f2bf(b) << 16);
    }
    unsigned short* ob = wt + (long)(n0 + rr) * D + k0 + cq * 16;
    uint4 v0 = {u[0], u[1], u[2], u[3]};
    uint4 v1 = {u[4], u[5], u[6], u[7]};
    *(uint4*)ob = v0;
    *((uint4*)ob + 1) = v1;
}

// ------------- K5: logits = mixed @ head_w + b (bf16 MFMA) + fused LSE partials
__global__ __launch_bounds__(256) void head_gemm_kernel(const unsigned short* __restrict__ A,
                                                        const unsigned short* __restrict__ Bt,
                                                        const float* __restrict__ bias,
                                                        float* __restrict__ C,
                                                        float* __restrict__ pm,
                                                        float* __restrict__ ps) {
    __shared__ unsigned short As[128 * 64];
    __shared__ unsigned short Bs[128 * 64];
    const int tid = threadIdx.x;
    const int mt = blockIdx.x & 7, nt = blockIdx.x >> 3;   // 8 m-tiles grouped for B L2 reuse
    const int m0 = mt * 128, n0 = nt * 128;
    const int wave = tid >> 6, lane = tid & 63;
    const int wm = wave >> 1, wn = wave & 1;
    const int quad = lane >> 4, l15 = lane & 15;
    floatx4 acc[4][4] = {};
    for (int k0 = 0; k0 < D; k0 += 64) {
#pragma unroll
        for (int s = 0; s < 4; s++) {
            int idx = s * 256 + tid;
            int row = idx >> 3, slot = idx & 7;
            int gch = slot ^ (row & 7);                    // XOR swizzle vs LDS slot
            const unsigned short* ga = A + (long)(m0 + row) * D + k0 + gch * 8;
            __builtin_amdgcn_global_load_lds(
                (const __attribute__((address_space(1))) unsigned int*)ga,
                (__attribute__((address_space(3))) unsigned int*)(As + idx * 8), 16, 0, 0);
            const unsigned short* gb = Bt + (long)(n0 + row) * D + k0 + gch * 8;
            __builtin_amdgcn_global_load_lds(
                (const __attribute__((address_space(1))) unsigned int*)gb,
                (__attribute__((address_space(3))) unsigned int*)(Bs + idx * 8), 16, 0, 0);
        }
        __syncthreads();
#pragma unroll
        for (int ks = 0; ks < 2; ks++) {
            short8 af[4], bfr[4];
            int q = ks * 4 + quad;
#pragma unroll
            for (int f = 0; f < 4; f++) {
                int ar = wm * 64 + f * 16 + l15;
                af[f] = *(const short8*)(As + ar * 64 + ((q ^ (ar & 7)) * 8));
                int br = wn * 64 + f * 16 + l15;
                bfr[f] = *(const short8*)(Bs + br * 64 + ((q ^ (br & 7)) * 8));
            }
#pragma unroll
            for (int fr = 0; fr < 4; fr++)
#pragma unroll
                for (int fc = 0; fc < 4; fc++)
                    acc[fr][fc] = __builtin_amdgcn_mfma_f32_16x16x32_bf16(af[fr], bfr[fc],
                                                                          acc[fr][fc], 0, 0, 0);
        }
        __syncthreads();
    }
    // epilogue: bias + store + per-row LSE partial over this wave's 64 cols
    float bv[4];
#pragma unroll
    for (int fc = 0; fc < 4; fc++) bv[fc] = bias[n0 + wn * 64 + fc * 16 + l15];
#pragma unroll
    for (int fr = 0; fr < 4; fr++) {
        int mr = m0 + wm * 64 + fr * 16 + quad * 4;
#pragma unroll
        for (int r = 0; r < 4; r++) {
            float v[4];
#pragma unroll
            for (int fc = 0; fc < 4; fc++) {
                v[fc] = acc[fr][fc][r] + bv[fc];
                C[(long)(mr + r) * V + n0 + wn * 64 + fc * 16 + l15] = v[fc];
            }
            float mx = fmaxf(fmaxf(v[0], v[1]), fmaxf(v[2], v[3]));
            mx = reduce16max(mx);
            float sv = __expf(v[0] - mx) + __expf(v[1] - mx)
                     + __expf(v[2] - mx) + __expf(v[3] - mx);
            sv = reduce16(sv);
            if (l15 == 0) {
                long row = mr + r;
                pm[row * NT2 + nt * 2 + wn] = mx;
                ps[row * NT2 + nt * 2 + wn] = sv;
            }
        }
    }
}

// ------------------- K6: combine LSE partials, atomicAdd mean loss
__device__ __forceinline__ void lse_comb(float& m, float& s, float m2, float s2) {
    float M = fmaxf(m, m2);
    s = s * __expf(m - M) + s2 * __expf(m2 - M);
    m = M;
}

__global__ __launch_bounds__(256) void loss_rows_kernel(const float* __restrict__ pm,
                                                        const float* __restrict__ ps,
                                                        const float* __restrict__ logits,
                                                        const int* __restrict__ targets,
                                                        float* __restrict__ loss_acc) {
    const int t = blockIdx.x, tid = threadIdx.x;
    float m = -INFINITY, s = 0.f;
    for (int i = tid; i < NT2; i += 256)
        lse_comb(m, s, pm[(long)t * NT2 + i], ps[(long)t * NT2 + i]);
#pragma unroll
    for (int msk = 1; msk <= 32; msk <<= 1) {
        float m2 = __shfl_xor(m, msk, 64);
        float s2 = __shfl_xor(s, msk, 64);
        lse_comb(m, s, m2, s2);
    }
    __shared__ float sm[4], ss[4];
    if ((tid & 63) == 0) { sm[tid >> 6] = m; ss[tid >> 6] = s; }
    __syncthreads();
    if (tid == 0) {
        float M = sm[0], S = ss[0];
#pragma unroll
        for (int w = 1; w < 4; w++) lse_comb(M, S, sm[w], ss[w]);
        float lse = M + __logf(S);
        float lt = logits[(long)t * V + targets[t]];
        atomicAdd(loss_acc, (lse - lt) * (1.0f / (float)T));
    }
}

// ------------------------------------------------------------------ launcher
extern "C" void kernel_launch(void* const* d_in, const int* in_sizes, int n_in,
                              void* d_out, int out_size, void* d_ws, size_t ws_size,
                              hipStream_t stream) {
    const int*   tokens  = (const int*)d_in[0];
    const int*   targets = (const int*)d_in[1];
    const float* embed   = (const float*)d_in[2];
    const float* fw_init = (const float*)d_in[3];
    const float* eta     = (const float*)d_in[4];
    const float* wa      = (const float*)d_in[5];
    const float* wb      = (const float*)d_in[6];
    const float* mlp_aw  = (const float*)d_in[7];
    const float* mlp_ab  = (const float*)d_in[8];
    const float* mlp_bw  = (const float*)d_in[9];
    const float* mlp_bb  = (const float*)d_in[10];
    const float* head_w  = (const float*)d_in[11];
    const float* head_b  = (const float*)d_in[12];
    float* out = (float*)d_out;                  // [T*V logits][1 loss]
    float* loss_acc = out + (long)T * V;

    // Workspace layout with overlays (stream-serial ordering guarantees
    // safety — each overlay's writer runs after the overlaid buffer is dead):
    //   xs    [gather .. mlp_fused]   0        .. 2 MB
    //   z0    [zgemm  .. scan]        2 MB     .. 4 MB
    //   z1    [zgemm  .. scan]        4 MB     .. 6 MB
    //   ypart [scan   .. mlp_fused]   6 MB     .. 38 MB   (16 planes, 32 MB)
    //   wt    [convert.. head]        2 MB     .. 33.25 MB (over z0/z1/ypart head)
    //   pm    [head   .. loss]        0        .. 2 MB     (over xs)
    //   ps    [head   .. loss]        36 MB    .. 38 MB    (over ypart tail)
    //   mixed [mlp    .. head]        38 MB    .. 39 MB
    char* ws = (char*)d_ws;
    float*          xs      = (float*)(ws + 0);
    float*          z0      = (float*)(ws + 2097152);
    float*          z1      = (float*)(ws + 4194304);
    float*          ypart   = (float*)(ws + 6291456);             // 32 MB
    unsigned short* wt      = (unsigned short*)(ws + 2097152);    // 32.75 MB
    float*          pm      = (float*)(ws + 0);                   // 2 MB
    float*          psum    = (float*)(ws + 37748736);            // 2 MB
    unsigned short* mixed   = (unsigned short*)(ws + 39845888);   // 1 MB

    // xs = embed[tokens]; zero loss accumulator
    gather_kernel<<<(T * D / 4) / 256, 256, 0, stream>>>(tokens, embed, xs, loss_acc);
    // z0 = eta*CC * xs@wa (pre-scaled for scan), z1 = xs@wb
    zgemm_kernel<<<dim3(D / 64, T / 32, 2), 256, 0, stream>>>(xs, wa, wb, eta, z0, z1);
    // sequential fast-weight scan -> 16 transposed partial-y planes
    scan_kernel<<<2048, 64, 0, stream>>>(z0, z1, xs, fw_init, ypart);
    // y = sum(partials)/CC; h = selu(y@Aw+Ab); mixed = bf16(0.5*(h@Bw+Bb)+0.5*xs)
    mlp_fused_kernel<<<T, 256, 0, stream>>>(ypart, xs, mlp_aw, mlp_ab, mlp_bw, mlp_bb, mixed);
    // head_w transpose+convert (after mlp so wt can overlay z0/z1/ypart)
    convert_wt_kernel<<<dim3(V / 64, D / 64), 256, 0, stream>>>(head_w, wt);
    // logits = mixed @ head_w + head_b, with fused per-tile LSE partials
    head_gemm_kernel<<<(T / 128) * (V / 128), 256, 0, stream>>>(mixed, wt, head_b, out, pm, psum);
    // loss: combine partials, atomic mean accumulate
    loss_rows_kernel<<<T, 256, 0, stream>>>(pm, psum, out, targets, loss_acc);
}

// Round 6
// 518.882 us; speedup vs baseline: 1.1005x; 1.1005x over previous
//
#include <hip/hip_runtime.h>

// Problem constants
#define D 512
#define H 20
#define V 32000
#define T 1024
#define NT2 500    // 2 * (V/128) lse partials per row

typedef unsigned int uint;
typedef __attribute__((ext_vector_type(8))) short short8;
typedef __attribute__((ext_vector_type(4))) float floatx4;

#define CC 2.8853900817779268f      // 2*log2(e)
#define M2C -5.7707801635558537f    // -2*CC

__device__ __forceinline__ unsigned short f2bf(float f) {
    unsigned u = __builtin_bit_cast(unsigned, f);
    u += 0x7fffu + ((u >> 16) & 1u);   // round-to-nearest-even
    return (unsigned short)(u >> 16);
}

// VALU-pipe cross-lane ops via DPP (no LDS pipe!)
template <int CTRL>
__device__ __forceinline__ float dpp_add(float v) {
    int x = __builtin_amdgcn_update_dpp(0, __builtin_bit_cast(int, v), CTRL, 0xf, 0xf, true);
    return v + __builtin_bit_cast(float, x);
}
template <int CTRL>
__device__ __forceinline__ float dpp_max(float v) {
    int x = __builtin_amdgcn_update_dpp(0, __builtin_bit_cast(int, v), CTRL, 0xf, 0xf, true);
    return fmaxf(v, __builtin_bit_cast(float, x));
}
// reduce 16 contiguous lanes -> all 16 hold the result
__device__ __forceinline__ float reduce16(float v) {
    v = dpp_add<0xB1>(v);    // quad_perm xor 1
    v = dpp_add<0x4E>(v);    // quad_perm xor 2
    v = dpp_add<0x141>(v);   // row_half_mirror
    v = dpp_add<0x140>(v);   // row_mirror
    return v;
}
__device__ __forceinline__ float reduce16max(float v) {
    v = dpp_max<0xB1>(v);
    v = dpp_max<0x4E>(v);
    v = dpp_max<0x141>(v);
    v = dpp_max<0x140>(v);
    return v;
}

// ---------------------------------------------------------------- K1: gather
__global__ __launch_bounds__(256) void gather_kernel(const int* __restrict__ tokens,
                                                     const float* __restrict__ embed,
                                                     float* __restrict__ xs) {
    int idx = blockIdx.x * 256 + threadIdx.x;     // float4 units, T*D/4 = 131072
    int row = idx >> 7;                            // D/4 = 128 float4 per row
    int c   = idx & 127;
    float4 v = ((const float4*)(embed + (long)tokens[row] * D))[c];
    ((float4*)xs)[idx] = v;
}

// ------------------------- K2: z0 = (eta*CC) * xs@wa ; z1 = xs@wb  (fp32)
// z0 pre-scaled so the scan's exp2 argument needs no extra multiplies.
__global__ __launch_bounds__(256) void zgemm_kernel(const float* __restrict__ xs,
                                                    const float* __restrict__ wa,
                                                    const float* __restrict__ wb,
                                                    const float* __restrict__ eta_p,
                                                    float* __restrict__ z0,
                                                    float* __restrict__ z1) {
    __shared__ float Xs[16 * 36];   // [k][m], 32 m, padded
    __shared__ float Ws[16 * 68];   // [k][n], 64 n, padded
    const int tid = threadIdx.x;
    const int n0 = blockIdx.x * 64, m0 = blockIdx.y * 32;
    const float* Wm = blockIdx.z ? wb : wa;
    float* Z = blockIdx.z ? z1 : z0;
    const float sc = blockIdx.z ? 1.0f : (*eta_p) * CC;
    const int tx = tid & 15, ty = tid >> 4;
    const int xr = tid >> 3, xk = (tid & 7) * 2;
    const int wr = tid >> 4, wc = (tid & 15) * 4;
    float acc[2][4] = {};
    for (int k0 = 0; k0 < D; k0 += 16) {
        float2 xv = *(const float2*)(xs + (m0 + xr) * D + k0 + xk);
        float4 wv = *(const float4*)(Wm + (k0 + wr) * D + n0 + wc);
        Xs[(xk + 0) * 36 + xr] = xv.x;
        Xs[(xk + 1) * 36 + xr] = xv.y;
        *(float4*)(Ws + wr * 68 + wc) = wv;
        __syncthreads();
#pragma unroll
        for (int k = 0; k < 16; k++) {
            float a0 = Xs[k * 36 + 2 * ty];
            float a1 = Xs[k * 36 + 2 * ty + 1];
            float4 b = *(const float4*)(Ws + k * 68 + tx * 4);
            float bv[4] = {b.x, b.y, b.z, b.w};
#pragma unroll
            for (int c = 0; c < 4; c++) {
                acc[0][c] = __builtin_fmaf(a0, bv[c], acc[0][c]);
                acc[1][c] = __builtin_fmaf(a1, bv[c], acc[1][c]);
            }
        }
        __syncthreads();
    }
    float4 v0 = {sc * acc[0][0], sc * acc[0][1], sc * acc[0][2], sc * acc[0][3]};
    float4 v1 = {sc * acc[1][0], sc * acc[1][1], sc * acc[1][2], sc * acc[1][3]};
    *(float4*)(Z + (m0 + 2 * ty + 0) * D + n0 + tx * 4) = v0;
    *(float4*)(Z + (m0 + 2 * ty + 1) * D + n0 + tx * 4) = v1;
}

// ------------------------------------------------------------------ K3: scan
// EXACT r1 structure (the only variant where the A/B double-buffer stays
// register-resident: VGPR 88, 160 us): 2048 single-wave blocks, lane owns
// fw[i0][j], fw[i0+64][j]; scalar loads; reduce16 + 2 shfl; lane-0 scalar
// stores to ypart[q][t][j]. Deltas vs r1: (a) z0 pre-scaled by eta*CC in
// zgemm (8 fewer muls/chunk); (b) XCD-locality swizzle — blocks sharing q
// read the SAME z0/xs rows, so pin each q-quarter to one XCD pair:
// xcd = 2q + (j&1); per-XCD L2 working set ~2 MB < 4 MB.
#define LOADC(B, tbase)                                        \
    {                                                          \
        _Pragma("unroll")                                      \
        for (int c = 0; c < 8; c++) {                          \
            const int tr = ((tbase) + c) * D;                  \
            za##B[c] = z0[tr + i0];                            \
            zb##B[c] = z0[tr + i1];                            \
            xa##B[c] = xs[tr + i0];                            \
            xb##B[c] = xs[tr + i1];                            \
            ez##B[c] = z1[tr + j];                             \
        }                                                      \
    }

#define COMPUTE(B, tbase)                                                     \
    {                                                                         \
        float p[8];                                                           \
        _Pragma("unroll")                                                     \
        for (int c = 0; c < 8; c++) {                                         \
            float e = ez##B[c];                                               \
            float a0 = __builtin_amdgcn_exp2f(__builtin_fmaf(e, za##B[c], g0)); \
            float a1 = __builtin_amdgcn_exp2f(__builtin_fmaf(e, zb##B[c], g1)); \
            float r0 = __builtin_amdgcn_rcpf(a0 + 1.0f);                      \
            float r1 = __builtin_amdgcn_rcpf(a1 + 1.0f);                      \
            g0 = __builtin_fmaf(M2C, r0, CC);                                 \
            g1 = __builtin_fmaf(M2C, r1, CC);                                 \
            p[c] = xa##B[c] * g0 + xb##B[c] * g1;                             \
        }                                                                     \
        _Pragma("unroll")                                                     \
        for (int c = 0; c < 8; c++) {                                         \
            float v = reduce16(p[c]);                                         \
            v += __shfl_xor(v, 16, 64);                                       \
            v += __shfl_xor(v, 32, 64);                                       \
            p[c] = v;                                                         \
        }                                                                     \
        if (lane == 0) {                                                      \
            _Pragma("unroll")                                                 \
            for (int c = 0; c < 8; c++) yp[((tbase) + c) * D] = p[c];         \
        }                                                                     \
    }

__global__ __launch_bounds__(64) void scan_kernel(const float* __restrict__ z0,
                                                  const float* __restrict__ z1,
                                                  const float* __restrict__ xs,
                                                  const float* __restrict__ fw_init,
                                                  float* __restrict__ ypart) {
    const int lane = threadIdx.x;          // 64
    const int bid = blockIdx.x;            // 2048
    // XCD-locality swizzle: xcd = bid&7 (dispatch heuristic), q = xcd>>1,
    // j = (idx<<1) | (xcd&1). Bijective on [0,2048).
    const int xcd = bid & 7, idx = bid >> 3;
    const int q = xcd >> 1;                // row quarter 0..3
    const int j = (idx << 1) | (xcd & 1);  // column 0..511
    const int i0 = q * 128 + lane;
    const int i1 = i0 + 64;
    float g0 = CC * fw_init[(long)i0 * D + j];   // pre-scaled state
    float g1 = CC * fw_init[(long)i1 * D + j];
    float* yp = ypart + (long)q * T * D + j;

    float zaA[8], zbA[8], xaA[8], xbA[8], ezA[8];
    float zaB[8], zbB[8], xaB[8], xbB[8], ezB[8];
    LOADC(A, 0);
    for (int t0 = 0; t0 < T; t0 += 16) {
        LOADC(B, t0 + 8);
        COMPUTE(A, t0);
        if (t0 + 16 < T) { LOADC(A, t0 + 16); }
        COMPUTE(B, t0 + 8);
    }
}

// ---------------- K4: fused MLP: y = sum(4 partials)/CC; h = selu(y@Aw+Ab);
//                   mixed = bf16(0.5*(h@Bw+Bb) + 0.5*xs). One block per token.
__global__ __launch_bounds__(256) void mlp_fused_kernel(const float* __restrict__ ypart,
                                                        const float* __restrict__ xs,
                                                        const float* __restrict__ Aw,
                                                        const float* __restrict__ Ab,
                                                        const float* __restrict__ Bw,
                                                        const float* __restrict__ Bb,
                                                        unsigned short* __restrict__ mixed) {
    const int t = blockIdx.x, tid = threadIdx.x;
    __shared__ float y_lds[D];
    __shared__ float h_lds[H];
    const float INVC = 0.34657359027997264f;   // 1/CC = ln2/2
    // phase 1: sum the 4 scan partials (coalesced), un-scale
#pragma unroll
    for (int s = 0; s < 2; s++) {
        int d = s * 256 + tid;
        float v = ypart[(0 * T + t) * D + d] + ypart[(1 * T + t) * D + d]
                + ypart[(2 * T + t) * D + d] + ypart[(3 * T + t) * D + d];
        y_lds[d] = v * INVC;
    }
    __syncthreads();
    // phase 2: h[20] — wave w computes jj = w*5..w*5+4 via full-wave dots
    const int w = tid >> 6, lane = tid & 63;
    float yv[8];
#pragma unroll
    for (int k = 0; k < 8; k++) yv[k] = y_lds[k * 64 + lane];
#pragma unroll
    for (int u = 0; u < 5; u++) {
        const int jj = w * 5 + u;
        float a = 0.f;
#pragma unroll
        for (int k = 0; k < 8; k++)
            a = __builtin_fmaf(yv[k], Aw[(k * 64 + lane) * H + jj], a);
        a = reduce16(a);
        a += __shfl_xor(a, 16, 64);
        a += __shfl_xor(a, 32, 64);
        if (lane == 0) {
            a += Ab[jj];
            const float sc = 1.0507009873554805f, al = 1.6732632423543772f;
            h_lds[jj] = a > 0.f ? sc * a : sc * al * (__expf(a) - 1.f);
        }
    }
    __syncthreads();
    // phase 3: mixed
#pragma unroll
    for (int s = 0; s < 2; s++) {
        int d = s * 256 + tid;
        float o = Bb[d];
#pragma unroll
        for (int jj = 0; jj < H; jj++) o = __builtin_fmaf(h_lds[jj], Bw[jj * D + d], o);
        int gi = t * D + d;
        mixed[gi] = f2bf(0.5f * o + 0.5f * xs[gi]);
    }
}

// --------------------------------- K5a: head_w [K][N] f32 -> wt [N][K] bf16
__global__ __launch_bounds__(256) void convert_wt_kernel(const float* __restrict__ head_w,
                                                         unsigned short* __restrict__ wt) {
    __shared__ float tile[64 * 68];
    const int n0 = blockIdx.x * 64, k0 = blockIdx.y * 64;
    const int tid = threadIdx.x;
#pragma unroll
    for (int s = 0; s < 4; s++) {
        int idx4 = s * 256 + tid;            // 1024 float4 slots
        int r = idx4 >> 4, c4 = idx4 & 15;
        float4 v = *(const float4*)(head_w + (long)(k0 + r) * V + n0 + c4 * 4);
        *(float4*)(tile + r * 68 + c4 * 4) = v;
    }
    __syncthreads();
    const int rr = tid >> 2;                 // n within tile
    const int cq = tid & 3;                  // k quarter (16 k's)
    uint u[8];
#pragma unroll
    for (int p = 0; p < 8; p++) {
        float a = tile[(cq * 16 + p * 2 + 0) * 68 + rr];
        float b = tile[(cq * 16 + p * 2 + 1) * 68 + rr];
        u[p] = (uint)f2bf(a) | ((uint)f2bf(b) << 16);
    }
    unsigned short* ob = wt + (long)(n0 + rr) * D + k0 + cq * 16;
    uint4 v0 = {u[0], u[1], u[2], u[3]};
    uint4 v1 = {u[4], u[5], u[6], u[7]};
    *(uint4*)ob = v0;
    *((uint4*)ob + 1) = v1;
}

// ------------- K5: logits = mixed @ head_w + b (bf16 MFMA) + fused LSE partials
__global__ __launch_bounds__(256) void head_gemm_kernel(const unsigned short* __restrict__ A,
                                                        const unsigned short* __restrict__ Bt,
                                                        const float* __restrict__ bias,
                                                        float* __restrict__ C,
                                                        float* __restrict__ pm,
                                                        float* __restrict__ ps) {
    __shared__ unsigned short As[128 * 64];
    __shared__ unsigned short Bs[128 * 64];
    const int tid = threadIdx.x;
    const int mt = blockIdx.x & 7, nt = blockIdx.x >> 3;   // 8 m-tiles grouped for B L2 reuse
    const int m0 = mt * 128, n0 = nt * 128;
    const int wave = tid >> 6, lane = tid & 63;
    const int wm = wave >> 1, wn = wave & 1;
    const int quad = lane >> 4, l15 = lane & 15;
    floatx4 acc[4][4] = {};
    for (int k0 = 0; k0 < D; k0 += 64) {
#pragma unroll
        for (int s = 0; s < 4; s++) {
            int idx = s * 256 + tid;
            int row = idx >> 3, slot = idx & 7;
            int gch = slot ^ (row & 7);                    // XOR swizzle vs LDS slot
            const unsigned short* ga = A + (long)(m0 + row) * D + k0 + gch * 8;
            __builtin_amdgcn_global_load_lds(
                (const __attribute__((address_space(1))) unsigned int*)ga,
                (__attribute__((address_space(3))) unsigned int*)(As + idx * 8), 16, 0, 0);
            const unsigned short* gb = Bt + (long)(n0 + row) * D + k0 + gch * 8;
            __builtin_amdgcn_global_load_lds(
                (const __attribute__((address_space(1))) unsigned int*)gb,
                (__attribute__((address_space(3))) unsigned int*)(Bs + idx * 8), 16, 0, 0);
        }
        __syncthreads();
#pragma unroll
        for (int ks = 0; ks < 2; ks++) {
            short8 af[4], bfr[4];
            int q = ks * 4 + quad;
#pragma unroll
            for (int f = 0; f < 4; f++) {
                int ar = wm * 64 + f * 16 + l15;
                af[f] = *(const short8*)(As + ar * 64 + ((q ^ (ar & 7)) * 8));
                int br = wn * 64 + f * 16 + l15;
                bfr[f] = *(const short8*)(Bs + br * 64 + ((q ^ (br & 7)) * 8));
            }
#pragma unroll
            for (int fr = 0; fr < 4; fr++)
#pragma unroll
                for (int fc = 0; fc < 4; fc++)
                    acc[fr][fc] = __builtin_amdgcn_mfma_f32_16x16x32_bf16(af[fr], bfr[fc],
                                                                          acc[fr][fc], 0, 0, 0);
        }
        __syncthreads();
    }
    // epilogue: bias + store + per-row LSE partial over this wave's 64 cols
    float bv[4];
#pragma unroll
    for (int fc = 0; fc < 4; fc++) bv[fc] = bias[n0 + wn * 64 + fc * 16 + l15];
#pragma unroll
    for (int fr = 0; fr < 4; fr++) {
        int mr = m0 + wm * 64 + fr * 16 + quad * 4;
#pragma unroll
        for (int r = 0; r < 4; r++) {
            float v[4];
#pragma unroll
            for (int fc = 0; fc < 4; fc++) {
                v[fc] = acc[fr][fc][r] + bv[fc];
                C[(long)(mr + r) * V + n0 + wn * 64 + fc * 16 + l15] = v[fc];
            }
            float mx = fmaxf(fmaxf(v[0], v[1]), fmaxf(v[2], v[3]));
            mx = reduce16max(mx);
            float sv = __expf(v[0] - mx) + __expf(v[1] - mx)
                     + __expf(v[2] - mx) + __expf(v[3] - mx);
            sv = reduce16(sv);
            if (l15 == 0) {
                long row = mr + r;
                pm[row * NT2 + nt * 2 + wn] = mx;
                ps[row * NT2 + nt * 2 + wn] = sv;
            }
        }
    }
}

// -------------------------------------------- K6: combine LSE partials + loss_t
__device__ __forceinline__ void lse_comb(float& m, float& s, float m2, float s2) {
    float M = fmaxf(m, m2);
    s = s * __expf(m - M) + s2 * __expf(m2 - M);
    m = M;
}

__global__ __launch_bounds__(256) void loss_rows_kernel(const float* __restrict__ pm,
                                                        const float* __restrict__ ps,
                                                        const float* __restrict__ logits,
                                                        const int* __restrict__ targets,
                                                        float* __restrict__ ws_loss) {
    const int t = blockIdx.x, tid = threadIdx.x;
    float m = -INFINITY, s = 0.f;
    for (int i = tid; i < NT2; i += 256)
        lse_comb(m, s, pm[(long)t * NT2 + i], ps[(long)t * NT2 + i]);
#pragma unroll
    for (int msk = 1; msk <= 32; msk <<= 1) {
        float m2 = __shfl_xor(m, msk, 64);
        float s2 = __shfl_xor(s, msk, 64);
        lse_comb(m, s, m2, s2);
    }
    __shared__ float sm[4], ss[4];
    if ((tid & 63) == 0) { sm[tid >> 6] = m; ss[tid >> 6] = s; }
    __syncthreads();
    if (tid == 0) {
        float M = sm[0], S = ss[0];
#pragma unroll
        for (int w = 1; w < 4; w++) lse_comb(M, S, sm[w], ss[w]);
        float lse = M + __logf(S);
        float lt = logits[(long)t * V + targets[t]];
        ws_loss[t] = lse - lt;   // -logp(target)
    }
}

__global__ __launch_bounds__(256) void loss_final_kernel(const float* __restrict__ ws_loss,
                                                         float* __restrict__ out) {
    const int tid = threadIdx.x;
    float s = 0.f;
    for (int i = tid; i < T; i += 256) s += ws_loss[i];
#pragma unroll
    for (int m = 1; m <= 32; m <<= 1) s += __shfl_xor(s, m, 64);
    __shared__ float red[4];
    if ((tid & 63) == 0) red[tid >> 6] = s;
    __syncthreads();
    if (tid == 0) out[0] = (red[0] + red[1] + red[2] + red[3]) * (1.f / (float)T);
}

// ------------------------------------------------------------------ launcher
extern "C" void kernel_launch(void* const* d_in, const int* in_sizes, int n_in,
                              void* d_out, int out_size, void* d_ws, size_t ws_size,
                              hipStream_t stream) {
    const int*   tokens  = (const int*)d_in[0];
    const int*   targets = (const int*)d_in[1];
    const float* embed   = (const float*)d_in[2];
    const float* fw_init = (const float*)d_in[3];
    const float* eta     = (const float*)d_in[4];
    const float* wa      = (const float*)d_in[5];
    const float* wb      = (const float*)d_in[6];
    const float* mlp_aw  = (const float*)d_in[7];
    const float* mlp_ab  = (const float*)d_in[8];
    const float* mlp_bw  = (const float*)d_in[9];
    const float* mlp_bb  = (const float*)d_in[10];
    const float* head_w  = (const float*)d_in[11];
    const float* head_b  = (const float*)d_in[12];
    float* out = (float*)d_out;                  // [T*V logits][1 loss]

    // Workspace layout with overlays (stream-serial ordering guarantees
    // safety — each overlay's writer runs after the overlaid buffer is dead):
    //   xs      [gather .. mlp]     0 .. 2 MB
    //   z0      [zgemm  .. scan]    2 .. 4 MB
    //   z1      [zgemm  .. scan]    4 .. 6 MB
    //   ypart   [scan   .. mlp]     6 .. 14 MB   (4 planes, [q][t][j])
    //   wt      [convert.. head]    2 .. 34.75 MB (over z0/z1/ypart)
    //   mixed   [mlp    .. head]    35 .. 36 MB
    //   pm      [head   .. loss]    0 .. 2 MB     (over xs)
    //   psum    [head   .. loss]    36 .. 38 MB
    //   ws_loss [loss]              38 MB
    char* ws = (char*)d_ws;
    float*          xs      = (float*)(ws + 0);
    float*          z0      = (float*)(ws + 2097152);
    float*          z1      = (float*)(ws + 4194304);
    float*          ypart   = (float*)(ws + 6291456);
    unsigned short* wt      = (unsigned short*)(ws + 2097152);
    unsigned short* mixed   = (unsigned short*)(ws + 36700160);
    float*          pm      = (float*)(ws + 0);
    float*          psum    = (float*)(ws + 37748736);
    float*          ws_loss = (float*)(ws + 39845888);

    // xs = embed[tokens]
    gather_kernel<<<(T * D / 4) / 256, 256, 0, stream>>>(tokens, embed, xs);
    // z0 = eta*CC * xs@wa (pre-scaled for scan), z1 = xs@wb
    zgemm_kernel<<<dim3(D / 64, T / 32, 2), 256, 0, stream>>>(xs, wa, wb, eta, z0, z1);
    // sequential fast-weight scan -> 4 partial y planes (r1 structure + XCD swizzle)
    scan_kernel<<<2048, 64, 0, stream>>>(z0, z1, xs, fw_init, ypart);
    // y = sum(partials)/CC; h = selu(y@Aw+Ab); mixed = bf16(0.5*(h@Bw+Bb)+0.5*xs)
    mlp_fused_kernel<<<T, 256, 0, stream>>>(ypart, xs, mlp_aw, mlp_ab, mlp_bw, mlp_bb, mixed);
    // head_w transpose+convert (after mlp so wt can overlay z0/z1/ypart)
    convert_wt_kernel<<<dim3(V / 64, D / 64), 256, 0, stream>>>(head_w, wt);
    // logits = mixed @ head_w + head_b, with fused per-tile LSE partials
    head_gemm_kernel<<<(T / 128) * (V / 128), 256, 0, stream>>>(mixed, wt, head_b, out, pm, psum);
    // loss: combine partials (2 MB read instead of 128 MB logits re-read)
    loss_rows_kernel<<<T, 256, 0, stream>>>(pm, psum, out, targets, ws_loss);
    loss_final_kernel<<<1, 256, 0, stream>>>(ws_loss, out + (long)T * V);
}